// Round 10
// baseline (144.607 us; speedup 1.0000x reference)
//
#include <hip/hip_runtime.h>

typedef __attribute__((ext_vector_type(4))) float f32x4;
typedef __attribute__((ext_vector_type(8))) short bf16x8;

#define T_LEN 2048
#define ENC   512
#define DEC   1024
#define ATT   128
#define NB    64
#define NTB   64             // 2048/32 row-tiles per batch
#define NSTEP 17             // 16 keys K-steps + 1 conv-tap step

__device__ __forceinline__ unsigned short f2bf_rne(float x) {
  unsigned int u = __builtin_bit_cast(unsigned int, x);
  u += 0x7fff + ((u >> 16) & 1);
  return (unsigned short)(u >> 16);
}
// round-half-up: same 0.5-ulp max error, 2 VALU ops
__device__ __forceinline__ short f2bf_fast(float x) {
  unsigned int u = __builtin_bit_cast(unsigned int, x);
  return (short)((u + 0x8000u) >> 16);
}

__device__ __forceinline__ float fast_tanh(float x) {
  float e = __expf(2.f * x);
  return 1.f - 2.f / (e + 1.f);    // robust at +-inf
}

// ---------------- prep: pq = query@W2 (blocks 0..63); Bl frag-exact (blocks 64..191)
// Bl (shorts): (((t*8 + n)*64 + lane)*8 + j), lane = grp*16+rsel; col = n*16+rsel,
// k = t*32 + grp*8 + j. Per (t,n): 64 lanes x 16B contiguous.
__global__ __launch_bounds__(128) void prep(
    const float* __restrict__ query, const float* __restrict__ W2,
    const float* __restrict__ W1, const float* __restrict__ convw,
    const float* __restrict__ ldense,
    float* __restrict__ pq, unsigned short* __restrict__ Bl) {
  int bidx = blockIdx.x;
  if (bidx < NB) {
    int a = threadIdx.x;
    const float* q = query + bidx * DEC;
    float a0 = 0.f, a1 = 0.f, a2 = 0.f, a3 = 0.f;
    for (int d = 0; d < DEC; d += 4) {
      a0 += q[d]     * W2[(d)     * ATT + a];
      a1 += q[d + 1] * W2[(d + 1) * ATT + a];
      a2 += q[d + 2] * W2[(d + 2) * ATT + a];
      a3 += q[d + 3] * W2[(d + 3) * ATT + a];
    }
    pq[bidx * ATT + a] = (a0 + a1) + (a2 + a3);
  } else {
    int a = bidx - NB;                   // output column 0..127
    int n = a >> 4, rs = a & 15;
    for (int k = threadIdx.x; k < NSTEP * 32; k += 128) {
      float v = 0.f;
      if (k < 512) {
        v = W1[k * ATT + a];
      } else if (k < 543) {
        int kc = k - 512;
        #pragma unroll
        for (int f = 0; f < 32; ++f) v += convw[f * 31 + kc] * ldense[f * ATT + a];
      }
      int t = k >> 5, g = (k & 31) >> 3, j = k & 7;
      Bl[(((t * 8 + n) * 64 + g * 16 + rs) << 3) + j] = f2bf_rne(v);
    }
  }
}

// ---------------- main: 1 wave/block (32 rows), B from L2, barrier-free unrolled loop
__global__ __launch_bounds__(64, 2) void lsa_main(
    const float* __restrict__ keys, const float* __restrict__ prev,
    const int* __restrict__ mask, const unsigned short* __restrict__ Bl,
    const float* __restrict__ pq, const float* __restrict__ Vv,
    float* __restrict__ wout, float* __restrict__ dpart, float* __restrict__ cpart) {
  __shared__ float e_vals[32];

  const int lane = threadIdx.x;
  const int bid = blockIdx.x;
  const int b = bid >> 6;
  const int row0 = (bid & 63) * 32;
  const int rsel = lane & 15, grp = lane >> 4;

  const float* keyrow = keys + ((size_t)b * T_LEN + row0 + rsel) * ENC + grp * 8;
  const unsigned short* Bp = Bl + lane * 8;

  f32x4 acc[2][8];
  #pragma unroll
  for (int m = 0; m < 2; ++m)
    #pragma unroll
    for (int n = 0; n < 8; ++n) acc[m][n] = (f32x4)0.f;

  // named register buffers: A-tiles 3-deep (A,B,C), B-tiles 2-deep (P,Q)
  f32x4 A0, A1, A2, A3, B0, B1, B2, B3, C0, C1, C2, C3;
  bf16x8 P0, P1, P2, P3, P4, P5, P6, P7;
  bf16x8 Q0, Q1, Q2, Q3, Q4, Q5, Q6, Q7;

#define LOADK(S, t_) do { \
    S##0 = *(const f32x4*)(keyrow + (t_) * 32); \
    S##1 = *(const f32x4*)(keyrow + (t_) * 32 + 4); \
    S##2 = *(const f32x4*)(keyrow + 16 * ENC + (t_) * 32); \
    S##3 = *(const f32x4*)(keyrow + 16 * ENC + (t_) * 32 + 4); } while (0)

#define LOADP(S) do { \
    _Pragma("unroll") \
    for (int j_ = 0; j_ < 4; ++j_) { \
      int kk0 = grp * 8 + j_, kk1 = grp * 8 + 4 + j_; \
      int p00 = row0 + rsel + kk0 - 15, p01 = row0 + rsel + kk1 - 15; \
      S##0[j_] = (kk0 < 31 && p00 >= 0 && p00 < T_LEN) ? prev[b * T_LEN + p00] : 0.f; \
      S##1[j_] = (kk1 < 31 && p01 >= 0 && p01 < T_LEN) ? prev[b * T_LEN + p01] : 0.f; \
      S##2[j_] = (kk0 < 31 && p00 + 16 >= 0 && p00 + 16 < T_LEN) ? prev[b * T_LEN + p00 + 16] : 0.f; \
      S##3[j_] = (kk1 < 31 && p01 + 16 >= 0 && p01 + 16 < T_LEN) ? prev[b * T_LEN + p01 + 16] : 0.f; \
    } } while (0)

#define LOADB(S, t_) do { \
    S##0 = *(const bf16x8*)(Bp + ((t_) * 8 + 0) * 512); \
    S##1 = *(const bf16x8*)(Bp + ((t_) * 8 + 1) * 512); \
    S##2 = *(const bf16x8*)(Bp + ((t_) * 8 + 2) * 512); \
    S##3 = *(const bf16x8*)(Bp + ((t_) * 8 + 3) * 512); \
    S##4 = *(const bf16x8*)(Bp + ((t_) * 8 + 4) * 512); \
    S##5 = *(const bf16x8*)(Bp + ((t_) * 8 + 5) * 512); \
    S##6 = *(const bf16x8*)(Bp + ((t_) * 8 + 6) * 512); \
    S##7 = *(const bf16x8*)(Bp + ((t_) * 8 + 7) * 512); } while (0)

#define STEP(S, BB) do { \
    bf16x8 af0, af1; \
    _Pragma("unroll") \
    for (int j_ = 0; j_ < 4; ++j_) { \
      af0[j_] = f2bf_fast(S##0[j_]); af0[4 + j_] = f2bf_fast(S##1[j_]); \
      af1[j_] = f2bf_fast(S##2[j_]); af1[4 + j_] = f2bf_fast(S##3[j_]); \
    } \
    acc[0][0] = __builtin_amdgcn_mfma_f32_16x16x32_bf16(af0, BB##0, acc[0][0], 0, 0, 0); \
    acc[1][0] = __builtin_amdgcn_mfma_f32_16x16x32_bf16(af1, BB##0, acc[1][0], 0, 0, 0); \
    acc[0][1] = __builtin_amdgcn_mfma_f32_16x16x32_bf16(af0, BB##1, acc[0][1], 0, 0, 0); \
    acc[1][1] = __builtin_amdgcn_mfma_f32_16x16x32_bf16(af1, BB##1, acc[1][1], 0, 0, 0); \
    acc[0][2] = __builtin_amdgcn_mfma_f32_16x16x32_bf16(af0, BB##2, acc[0][2], 0, 0, 0); \
    acc[1][2] = __builtin_amdgcn_mfma_f32_16x16x32_bf16(af1, BB##2, acc[1][2], 0, 0, 0); \
    acc[0][3] = __builtin_amdgcn_mfma_f32_16x16x32_bf16(af0, BB##3, acc[0][3], 0, 0, 0); \
    acc[1][3] = __builtin_amdgcn_mfma_f32_16x16x32_bf16(af1, BB##3, acc[1][3], 0, 0, 0); \
    acc[0][4] = __builtin_amdgcn_mfma_f32_16x16x32_bf16(af0, BB##4, acc[0][4], 0, 0, 0); \
    acc[1][4] = __builtin_amdgcn_mfma_f32_16x16x32_bf16(af1, BB##4, acc[1][4], 0, 0, 0); \
    acc[0][5] = __builtin_amdgcn_mfma_f32_16x16x32_bf16(af0, BB##5, acc[0][5], 0, 0, 0); \
    acc[1][5] = __builtin_amdgcn_mfma_f32_16x16x32_bf16(af1, BB##5, acc[1][5], 0, 0, 0); \
    acc[0][6] = __builtin_amdgcn_mfma_f32_16x16x32_bf16(af0, BB##6, acc[0][6], 0, 0, 0); \
    acc[1][6] = __builtin_amdgcn_mfma_f32_16x16x32_bf16(af1, BB##6, acc[1][6], 0, 0, 0); \
    acc[0][7] = __builtin_amdgcn_mfma_f32_16x16x32_bf16(af0, BB##7, acc[0][7], 0, 0, 0); \
    acc[1][7] = __builtin_amdgcn_mfma_f32_16x16x32_bf16(af1, BB##7, acc[1][7], 0, 0, 0); } while (0)

  // prologue: A-tiles 0,1 and B-tile 0 in flight
  LOADK(A, 0); LOADK(B, 1); LOADB(P, 0);
  // 17 steps, prefetch A 2 ahead / B 1 ahead, zero barriers
  LOADK(C, 2);  LOADB(Q, 1);  STEP(A, P);
  LOADK(A, 3);  LOADB(P, 2);  STEP(B, Q);
  LOADK(B, 4);  LOADB(Q, 3);  STEP(C, P);
  LOADK(C, 5);  LOADB(P, 4);  STEP(A, Q);
  LOADK(A, 6);  LOADB(Q, 5);  STEP(B, P);
  LOADK(B, 7);  LOADB(P, 6);  STEP(C, Q);
  LOADK(C, 8);  LOADB(Q, 7);  STEP(A, P);
  LOADK(A, 9);  LOADB(P, 8);  STEP(B, Q);
  LOADK(B, 10); LOADB(Q, 9);  STEP(C, P);
  LOADK(C, 11); LOADB(P, 10); STEP(A, Q);
  LOADK(A, 12); LOADB(Q, 11); STEP(B, P);
  LOADK(B, 13); LOADB(P, 12); STEP(C, Q);
  LOADK(C, 14); LOADB(Q, 13); STEP(A, P);
  LOADK(A, 15); LOADB(P, 14); STEP(B, Q);
  LOADP(B);     LOADB(Q, 15); STEP(C, P);
  LOADB(P, 16); STEP(A, Q);
  STEP(B, P);

  // ---- epilogue: scores = sum_c V[c]*tanh(acc + pq[c]) over all 128 cols ----
  float psum[2][4];
  #pragma unroll
  for (int m = 0; m < 2; ++m)
    #pragma unroll
    for (int i = 0; i < 4; ++i) psum[m][i] = 0.f;
  #pragma unroll
  for (int n = 0; n < 8; ++n) {
    int c = n * 16 + rsel;
    float pqv = pq[b * ATT + c];
    float vv = Vv[c];
    #pragma unroll
    for (int m = 0; m < 2; ++m)
      #pragma unroll
      for (int i = 0; i < 4; ++i)
        psum[m][i] += vv * fast_tanh(acc[m][n][i] + pqv);
  }
  #pragma unroll
  for (int m = 0; m < 2; ++m)
    #pragma unroll
    for (int i = 0; i < 4; ++i) {
      float v = psum[m][i];
      v += __shfl_xor(v, 1, 64);
      v += __shfl_xor(v, 2, 64);
      v += __shfl_xor(v, 4, 64);
      v += __shfl_xor(v, 8, 64);
      psum[m][i] = v;
    }
  float esum = 0.f;
  if (rsel == 0) {
    #pragma unroll
    for (int m = 0; m < 2; ++m)
      #pragma unroll
      for (int i = 0; i < 4; ++i) {
        int r = m * 16 + grp * 4 + i;
        int gr = b * T_LEN + row0 + r;
        float e = (mask[gr] == 0) ? 0.f : __expf(psum[m][i]);
        wout[gr] = e;        // unnormalized; finalize scales
        e_vals[r] = e;
        esum += e;
      }
  }
  // block-total of e (lanes 0,16,32,48 hold partials; others contribute 0)
  esum += __shfl_xor(esum, 16, 64);
  esum += __shfl_xor(esum, 32, 64);
  if (lane == 0) dpart[bid] = esum;
  __syncthreads();

  // ---- partial context over own 32 rows; skip masked rows (wave-uniform) ----
  {
    const float* kb = keys + ((size_t)b * T_LEN + row0) * ENC + lane * 8;
    f32x4 c0 = (f32x4)0.f, c1 = (f32x4)0.f;
    #pragma unroll 4
    for (int r = 0; r < 32; ++r) {
      float e = e_vals[r];
      if (e != 0.f) {
        f32x4 k0 = *(const f32x4*)(kb + (size_t)r * ENC);
        f32x4 k1 = *(const f32x4*)(kb + (size_t)r * ENC + 4);
        c0 += e * k0;
        c1 += e * k1;
      }
    }
    *(f32x4*)(cpart + (size_t)bid * ENC + lane * 8) = c0;
    *(f32x4*)(cpart + (size_t)bid * ENC + lane * 8 + 4) = c1;
  }
}

// ---------------- finalize: normalize weights + reduce context partials
__global__ __launch_bounds__(256) void lsa_finalize(
    const float* __restrict__ dpart, const float* __restrict__ cpart,
    float* __restrict__ out) {
  int b = blockIdx.x, tid = threadIdx.x;
  float d = 0.f;
  #pragma unroll
  for (int i = 0; i < NTB; ++i) d += dpart[b * NTB + i];
  float inv = 1.f / d;
  for (int e = tid; e < ENC; e += 256) {
    float c = 0.f;
    #pragma unroll
    for (int i = 0; i < NTB; ++i) c += cpart[((size_t)(b * NTB + i)) * ENC + e];
    out[b * ENC + e] = c * inv;
  }
  float* wrow = out + NB * ENC + (size_t)b * T_LEN;
  for (int t = tid; t < T_LEN; t += 256) wrow[t] *= inv;
}

extern "C" void kernel_launch(void* const* d_in, const int* in_sizes, int n_in,
                              void* d_out, int out_size, void* d_ws, size_t ws_size,
                              hipStream_t stream) {
  const float* query  = (const float*)d_in[0];
  const float* keys   = (const float*)d_in[1];
  const float* prev   = (const float*)d_in[2];
  const int*   mask   = (const int*)d_in[3];
  const float* W1     = (const float*)d_in[4];
  const float* W2     = (const float*)d_in[5];
  const float* V      = (const float*)d_in[6];
  const float* convw  = (const float*)d_in[7];
  const float* ldense = (const float*)d_in[8];
  float* out = (float*)d_out;

  char* ws = (char*)d_ws;
  unsigned short* Bl = (unsigned short*)ws;                       // 139264 B
  float* pq    = (float*)(ws + 139264);                           // 32768 B
  float* dpart = (float*)(ws + 139264 + 32768);                   // 16384 B
  float* cpart = (float*)(ws + 139264 + 32768 + 16384);           // 8 MB

  prep<<<dim3(192), dim3(128), 0, stream>>>(query, W2, W1, convw, ldense, pq, Bl);
  lsa_main<<<dim3(NB * NTB), dim3(64), 0, stream>>>(keys, prev, mask, Bl, pq, V,
                                                    out + NB * ENC, dpart, cpart);
  lsa_finalize<<<dim3(NB), dim3(256), 0, stream>>>(dpart, cpart, out);
}

// Round 11
// 137.738 us; speedup vs baseline: 1.0499x; 1.0499x over previous
//
#include <hip/hip_runtime.h>

typedef __attribute__((ext_vector_type(4))) float f32x4;
typedef __attribute__((ext_vector_type(8))) short bf16x8;

#define T_LEN 2048
#define ENC   512
#define DEC   1024
#define ATT   128
#define NB    64
#define NTB   64             // 2048/32 row-tiles per batch
#define NSTEP 17             // 16 keys K-steps + 1 conv-tap step

__device__ __forceinline__ unsigned short f2bf_rne(float x) {
  unsigned int u = __builtin_bit_cast(unsigned int, x);
  u += 0x7fff + ((u >> 16) & 1);
  return (unsigned short)(u >> 16);
}
// round-half-up: same 0.5-ulp max error, 2 VALU ops
__device__ __forceinline__ short f2bf_fast(float x) {
  unsigned int u = __builtin_bit_cast(unsigned int, x);
  return (short)((u + 0x8000u) >> 16);
}

__device__ __forceinline__ float fast_tanh(float x) {
  float e = __expf(2.f * x);
  return 1.f - 2.f / (e + 1.f);    // robust at +-inf
}

// ---------------- prep: pq = query@W2 (blocks 0..63); Bl frag-exact (blocks 64..191)
// Bl (shorts): (((t*8 + n)*64 + lane)*8 + j), lane = grp*16+rsel; col = n*16+rsel,
// k = t*32 + grp*8 + j. Per (t,n): 64 lanes x 16B contiguous.
__global__ __launch_bounds__(128) void prep(
    const float* __restrict__ query, const float* __restrict__ W2,
    const float* __restrict__ W1, const float* __restrict__ convw,
    const float* __restrict__ ldense,
    float* __restrict__ pq, unsigned short* __restrict__ Bl) {
  int bidx = blockIdx.x;
  if (bidx < NB) {
    int a = threadIdx.x;
    const float* q = query + bidx * DEC;
    float a0 = 0.f, a1 = 0.f, a2 = 0.f, a3 = 0.f;
    for (int d = 0; d < DEC; d += 4) {
      a0 += q[d]     * W2[(d)     * ATT + a];
      a1 += q[d + 1] * W2[(d + 1) * ATT + a];
      a2 += q[d + 2] * W2[(d + 2) * ATT + a];
      a3 += q[d + 3] * W2[(d + 3) * ATT + a];
    }
    pq[bidx * ATT + a] = (a0 + a1) + (a2 + a3);
  } else {
    int a = bidx - NB;                   // output column 0..127
    int n = a >> 4, rs = a & 15;
    for (int k = threadIdx.x; k < NSTEP * 32; k += 128) {
      float v = 0.f;
      if (k < 512) {
        v = W1[k * ATT + a];
      } else if (k < 543) {
        int kc = k - 512;
        #pragma unroll
        for (int f = 0; f < 32; ++f) v += convw[f * 31 + kc] * ldense[f * ATT + a];
      }
      int t = k >> 5, g = (k & 31) >> 3, j = k & 7;
      Bl[(((t * 8 + n) * 64 + g * 16 + rs) << 3) + j] = f2bf_rne(v);
    }
  }
}

// ---------------- main: 1 wave/block, named-reg pipeline PINNED by sched_barrier ----
__global__ __launch_bounds__(64, 2) void lsa_main(
    const float* __restrict__ keys, const float* __restrict__ prev,
    const int* __restrict__ mask, const unsigned short* __restrict__ Bl,
    const float* __restrict__ pq, const float* __restrict__ Vv,
    float* __restrict__ wout, float* __restrict__ dpart, float* __restrict__ cpart) {
  __shared__ float e_vals[32];

  const int lane = threadIdx.x;
  const int bid = blockIdx.x;
  const int b = bid >> 6;
  const int row0 = (bid & 63) * 32;
  const int rsel = lane & 15, grp = lane >> 4;

  const float* keyrow = keys + ((size_t)b * T_LEN + row0 + rsel) * ENC + grp * 8;
  const unsigned short* Bp = Bl + lane * 8;

  f32x4 acc[2][8];
  #pragma unroll
  for (int m = 0; m < 2; ++m)
    #pragma unroll
    for (int n = 0; n < 8; ++n) acc[m][n] = (f32x4)0.f;

  // named register buffers: A-tiles 3-deep (A,B,C), B-tiles 2-deep (P,Q)
  f32x4 A0, A1, A2, A3, B0, B1, B2, B3, C0, C1, C2, C3;
  bf16x8 P0, P1, P2, P3, P4, P5, P6, P7;
  bf16x8 Q0, Q1, Q2, Q3, Q4, Q5, Q6, Q7;

#define SB() __builtin_amdgcn_sched_barrier(0)

#define LOADK(S, t_) do { \
    S##0 = *(const f32x4*)(keyrow + (t_) * 32); \
    S##1 = *(const f32x4*)(keyrow + (t_) * 32 + 4); \
    S##2 = *(const f32x4*)(keyrow + 16 * ENC + (t_) * 32); \
    S##3 = *(const f32x4*)(keyrow + 16 * ENC + (t_) * 32 + 4); } while (0)

#define LOADP(S) do { \
    _Pragma("unroll") \
    for (int j_ = 0; j_ < 4; ++j_) { \
      int kk0 = grp * 8 + j_, kk1 = grp * 8 + 4 + j_; \
      int p00 = row0 + rsel + kk0 - 15, p01 = row0 + rsel + kk1 - 15; \
      S##0[j_] = (kk0 < 31 && p00 >= 0 && p00 < T_LEN) ? prev[b * T_LEN + p00] : 0.f; \
      S##1[j_] = (kk1 < 31 && p01 >= 0 && p01 < T_LEN) ? prev[b * T_LEN + p01] : 0.f; \
      S##2[j_] = (kk0 < 31 && p00 + 16 >= 0 && p00 + 16 < T_LEN) ? prev[b * T_LEN + p00 + 16] : 0.f; \
      S##3[j_] = (kk1 < 31 && p01 + 16 >= 0 && p01 + 16 < T_LEN) ? prev[b * T_LEN + p01 + 16] : 0.f; \
    } } while (0)

#define LOADB(S, t_) do { \
    S##0 = *(const bf16x8*)(Bp + ((t_) * 8 + 0) * 512); \
    S##1 = *(const bf16x8*)(Bp + ((t_) * 8 + 1) * 512); \
    S##2 = *(const bf16x8*)(Bp + ((t_) * 8 + 2) * 512); \
    S##3 = *(const bf16x8*)(Bp + ((t_) * 8 + 3) * 512); \
    S##4 = *(const bf16x8*)(Bp + ((t_) * 8 + 4) * 512); \
    S##5 = *(const bf16x8*)(Bp + ((t_) * 8 + 5) * 512); \
    S##6 = *(const bf16x8*)(Bp + ((t_) * 8 + 6) * 512); \
    S##7 = *(const bf16x8*)(Bp + ((t_) * 8 + 7) * 512); } while (0)

#define STEP(S, BB) do { \
    bf16x8 af0, af1; \
    _Pragma("unroll") \
    for (int j_ = 0; j_ < 4; ++j_) { \
      af0[j_] = f2bf_fast(S##0[j_]); af0[4 + j_] = f2bf_fast(S##1[j_]); \
      af1[j_] = f2bf_fast(S##2[j_]); af1[4 + j_] = f2bf_fast(S##3[j_]); \
    } \
    acc[0][0] = __builtin_amdgcn_mfma_f32_16x16x32_bf16(af0, BB##0, acc[0][0], 0, 0, 0); \
    acc[1][0] = __builtin_amdgcn_mfma_f32_16x16x32_bf16(af1, BB##0, acc[1][0], 0, 0, 0); \
    acc[0][1] = __builtin_amdgcn_mfma_f32_16x16x32_bf16(af0, BB##1, acc[0][1], 0, 0, 0); \
    acc[1][1] = __builtin_amdgcn_mfma_f32_16x16x32_bf16(af1, BB##1, acc[1][1], 0, 0, 0); \
    acc[0][2] = __builtin_amdgcn_mfma_f32_16x16x32_bf16(af0, BB##2, acc[0][2], 0, 0, 0); \
    acc[1][2] = __builtin_amdgcn_mfma_f32_16x16x32_bf16(af1, BB##2, acc[1][2], 0, 0, 0); \
    acc[0][3] = __builtin_amdgcn_mfma_f32_16x16x32_bf16(af0, BB##3, acc[0][3], 0, 0, 0); \
    acc[1][3] = __builtin_amdgcn_mfma_f32_16x16x32_bf16(af1, BB##3, acc[1][3], 0, 0, 0); \
    acc[0][4] = __builtin_amdgcn_mfma_f32_16x16x32_bf16(af0, BB##4, acc[0][4], 0, 0, 0); \
    acc[1][4] = __builtin_amdgcn_mfma_f32_16x16x32_bf16(af1, BB##4, acc[1][4], 0, 0, 0); \
    acc[0][5] = __builtin_amdgcn_mfma_f32_16x16x32_bf16(af0, BB##5, acc[0][5], 0, 0, 0); \
    acc[1][5] = __builtin_amdgcn_mfma_f32_16x16x32_bf16(af1, BB##5, acc[1][5], 0, 0, 0); \
    acc[0][6] = __builtin_amdgcn_mfma_f32_16x16x32_bf16(af0, BB##6, acc[0][6], 0, 0, 0); \
    acc[1][6] = __builtin_amdgcn_mfma_f32_16x16x32_bf16(af1, BB##6, acc[1][6], 0, 0, 0); \
    acc[0][7] = __builtin_amdgcn_mfma_f32_16x16x32_bf16(af0, BB##7, acc[0][7], 0, 0, 0); \
    acc[1][7] = __builtin_amdgcn_mfma_f32_16x16x32_bf16(af1, BB##7, acc[1][7], 0, 0, 0); } while (0)

  // prologue: A-tiles 0,1 and B-tile 0 in flight
  LOADK(A, 0); LOADK(B, 1); LOADB(P, 0);
  // 17 steps; loads issued 2(A)/1(B) ahead and PINNED above each STEP by sched_barrier(0)
  LOADK(C, 2);  LOADB(Q, 1);  SB(); STEP(A, P);
  LOADK(A, 3);  LOADB(P, 2);  SB(); STEP(B, Q);
  LOADK(B, 4);  LOADB(Q, 3);  SB(); STEP(C, P);
  LOADK(C, 5);  LOADB(P, 4);  SB(); STEP(A, Q);
  LOADK(A, 6);  LOADB(Q, 5);  SB(); STEP(B, P);
  LOADK(B, 7);  LOADB(P, 6);  SB(); STEP(C, Q);
  LOADK(C, 8);  LOADB(Q, 7);  SB(); STEP(A, P);
  LOADK(A, 9);  LOADB(P, 8);  SB(); STEP(B, Q);
  LOADK(B, 10); LOADB(Q, 9);  SB(); STEP(C, P);
  LOADK(C, 11); LOADB(P, 10); SB(); STEP(A, Q);
  LOADK(A, 12); LOADB(Q, 11); SB(); STEP(B, P);
  LOADK(B, 13); LOADB(P, 12); SB(); STEP(C, Q);
  LOADK(C, 14); LOADB(Q, 13); SB(); STEP(A, P);
  LOADK(A, 15); LOADB(P, 14); SB(); STEP(B, Q);
  LOADP(B);     LOADB(Q, 15); SB(); STEP(C, P);
  LOADB(P, 16); SB(); STEP(A, Q);
  STEP(B, P);

  // ---- epilogue: scores = sum_c V[c]*tanh(acc + pq[c]) over all 128 cols ----
  float psum[2][4];
  #pragma unroll
  for (int m = 0; m < 2; ++m)
    #pragma unroll
    for (int i = 0; i < 4; ++i) psum[m][i] = 0.f;
  #pragma unroll
  for (int n = 0; n < 8; ++n) {
    int c = n * 16 + rsel;
    float pqv = pq[b * ATT + c];
    float vv = Vv[c];
    #pragma unroll
    for (int m = 0; m < 2; ++m)
      #pragma unroll
      for (int i = 0; i < 4; ++i)
        psum[m][i] += vv * fast_tanh(acc[m][n][i] + pqv);
  }
  #pragma unroll
  for (int m = 0; m < 2; ++m)
    #pragma unroll
    for (int i = 0; i < 4; ++i) {
      float v = psum[m][i];
      v += __shfl_xor(v, 1, 64);
      v += __shfl_xor(v, 2, 64);
      v += __shfl_xor(v, 4, 64);
      v += __shfl_xor(v, 8, 64);
      psum[m][i] = v;
    }
  float esum = 0.f;
  if (rsel == 0) {
    #pragma unroll
    for (int m = 0; m < 2; ++m)
      #pragma unroll
      for (int i = 0; i < 4; ++i) {
        int r = m * 16 + grp * 4 + i;
        int gr = b * T_LEN + row0 + r;
        float e = (mask[gr] == 0) ? 0.f : __expf(psum[m][i]);
        wout[gr] = e;        // unnormalized; finalize scales
        e_vals[r] = e;
        esum += e;
      }
  }
  // block-total of e (lanes 0,16,32,48 hold partials; others contribute 0)
  esum += __shfl_xor(esum, 16, 64);
  esum += __shfl_xor(esum, 32, 64);
  if (lane == 0) dpart[bid] = esum;
  __syncthreads();

  // ---- partial context over own 32 rows: branch-free, fully unrolled, pipelined ----
  {
    const float* kb = keys + ((size_t)b * T_LEN + row0) * ENC + lane * 8;
    f32x4 c0 = (f32x4)0.f, c1 = (f32x4)0.f;
    #pragma unroll
    for (int r = 0; r < 32; ++r) {
      float e = e_vals[r];
      f32x4 k0 = *(const f32x4*)(kb + (size_t)r * ENC);
      f32x4 k1 = *(const f32x4*)(kb + (size_t)r * ENC + 4);
      c0 += e * k0;
      c1 += e * k1;
    }
    *(f32x4*)(cpart + (size_t)bid * ENC + lane * 8) = c0;
    *(f32x4*)(cpart + (size_t)bid * ENC + lane * 8 + 4) = c1;
  }
}

// ---------------- finalize: normalize weights + reduce context partials
__global__ __launch_bounds__(256) void lsa_finalize(
    const float* __restrict__ dpart, const float* __restrict__ cpart,
    float* __restrict__ out) {
  int b = blockIdx.x, tid = threadIdx.x;
  float d = 0.f;
  #pragma unroll
  for (int i = 0; i < NTB; ++i) d += dpart[b * NTB + i];
  float inv = 1.f / d;
  for (int e = tid; e < ENC; e += 256) {
    float c = 0.f;
    #pragma unroll
    for (int i = 0; i < NTB; ++i) c += cpart[((size_t)(b * NTB + i)) * ENC + e];
    out[b * ENC + e] = c * inv;
  }
  float* wrow = out + NB * ENC + (size_t)b * T_LEN;
  for (int t = tid; t < T_LEN; t += 256) wrow[t] *= inv;
}

extern "C" void kernel_launch(void* const* d_in, const int* in_sizes, int n_in,
                              void* d_out, int out_size, void* d_ws, size_t ws_size,
                              hipStream_t stream) {
  const float* query  = (const float*)d_in[0];
  const float* keys   = (const float*)d_in[1];
  const float* prev   = (const float*)d_in[2];
  const int*   mask   = (const int*)d_in[3];
  const float* W1     = (const float*)d_in[4];
  const float* W2     = (const float*)d_in[5];
  const float* V      = (const float*)d_in[6];
  const float* convw  = (const float*)d_in[7];
  const float* ldense = (const float*)d_in[8];
  float* out = (float*)d_out;

  char* ws = (char*)d_ws;
  unsigned short* Bl = (unsigned short*)ws;                       // 139264 B
  float* pq    = (float*)(ws + 139264);                           // 32768 B
  float* dpart = (float*)(ws + 139264 + 32768);                   // 16384 B
  float* cpart = (float*)(ws + 139264 + 32768 + 16384);           // 8 MB

  prep<<<dim3(192), dim3(128), 0, stream>>>(query, W2, W1, convw, ldense, pq, Bl);
  lsa_main<<<dim3(NB * NTB), dim3(64), 0, stream>>>(keys, prev, mask, Bl, pq, V,
                                                    out + NB * ENC, dpart, cpart);
  lsa_finalize<<<dim3(NB), dim3(256), 0, stream>>>(dpart, cpart, out);
}

// Round 13
// 136.502 us; speedup vs baseline: 1.0594x; 1.0091x over previous
//
#include <hip/hip_runtime.h>

typedef __attribute__((ext_vector_type(4))) float f32x4;
typedef __attribute__((ext_vector_type(8))) short bf16x8;

#define T_LEN 2048
#define ENC   512
#define DEC   1024
#define ATT   128
#define NB    64
#define NTB   64             // 2048/32 row-tiles per batch
#define NSTEP 17

typedef unsigned int u32;
typedef __attribute__((address_space(1))) const u32 gu32;
typedef __attribute__((address_space(3))) u32 lu32;

__device__ __forceinline__ void async_copy16(const void* g, void* l) {
  __builtin_amdgcn_global_load_lds((gu32*)g, (lu32*)l, 16, 0, 0);
}

__device__ __forceinline__ unsigned short f2bf_rne(float x) {
  unsigned int u = __builtin_bit_cast(unsigned int, x);
  u += 0x7fff + ((u >> 16) & 1);
  return (unsigned short)(u >> 16);
}
__device__ __forceinline__ short f2bf_fast(float x) {
  unsigned int u = __builtin_bit_cast(unsigned int, x);
  return (short)((u + 0x8000u) >> 16);
}
__device__ __forceinline__ float fast_tanh(float x) {
  float e = __expf(2.f * x);
  return 1.f - 2.f / (e + 1.f);
}

// ---------------- prep: pq = query@W2 (blocks 0..63); Bl frag-exact (blocks 64..191)
// Bl (shorts): (((t*8 + n)*64 + grp*16 + rsel)*8 + j); col = n*16+rsel, k = t*32+grp*8+j
__global__ __launch_bounds__(128) void prep(
    const float* __restrict__ query, const float* __restrict__ W2,
    const float* __restrict__ W1, const float* __restrict__ convw,
    const float* __restrict__ ldense,
    float* __restrict__ pq, unsigned short* __restrict__ Bl) {
  int bidx = blockIdx.x;
  if (bidx < NB) {
    int a = threadIdx.x;
    const float* q = query + bidx * DEC;
    float a0 = 0.f, a1 = 0.f, a2 = 0.f, a3 = 0.f;
    for (int d = 0; d < DEC; d += 4) {
      a0 += q[d]     * W2[(d)     * ATT + a];
      a1 += q[d + 1] * W2[(d + 1) * ATT + a];
      a2 += q[d + 2] * W2[(d + 2) * ATT + a];
      a3 += q[d + 3] * W2[(d + 3) * ATT + a];
    }
    pq[bidx * ATT + a] = (a0 + a1) + (a2 + a3);
  } else {
    int a = bidx - NB;
    int n = a >> 4, rs = a & 15;
    for (int k = threadIdx.x; k < NSTEP * 32; k += 128) {
      float v = 0.f;
      if (k < 512) {
        v = W1[k * ATT + a];
      } else if (k < 543) {
        int kc = k - 512;
        #pragma unroll
        for (int f = 0; f < 32; ++f) v += convw[f * 31 + kc] * ldense[f * ATT + a];
      }
      int t = k >> 5, g = (k & 31) >> 3, j = k & 7;
      Bl[(((t * 8 + n) * 64 + g * 16 + rs) << 3) + j] = f2bf_rne(v);
    }
  }
}

// ---------------- main: 1-wave blocks, ALL counted ops are global_load_lds, counted vmcnt, no barriers
__global__ __launch_bounds__(64) void lsa_main(
    const float* __restrict__ keys, const float* __restrict__ prev,
    const int* __restrict__ mask, const unsigned short* __restrict__ Bl,
    const float* __restrict__ pq, const float* __restrict__ Vv,
    float* __restrict__ wout, float* __restrict__ dpart, float* __restrict__ cpart) {
  // LDS: A ring 3x4096 @0, B ring 2x8192 @12288, B16 slot @28672, e_vals @36864
  __shared__ f32x4 SHv[2312];   // 36992 B
  char* SHc = (char*)SHv;

  const int lane = threadIdx.x;
  const int bid = blockIdx.x;
  const int b = bid >> 6;
  const int row0 = (bid & 63) * 32;
  const int rsel = lane & 15, grp = lane >> 4;
  const int lr = lane >> 3, cp = lane & 7;
  const int gc = cp ^ lr;                     // pre-swizzled global chunk (phys c' holds c'^(row&7))
  const int ca0 = (2 * grp) ^ (rsel & 7);     // read-side phys chunks
  const int ca1 = ca0 ^ 1;

  const float* gAsrc = keys + ((size_t)b * T_LEN + row0 + lr) * ENC + gc * 4;
  const unsigned short* Bsrc = Bl + lane * 8;

  f32x4 acc[2][8];
  #pragma unroll
  for (int m = 0; m < 2; ++m)
    #pragma unroll
    for (int n = 0; n < 8; ++n) acc[m][n] = (f32x4)0.f;

#define WAITVM_(n) asm volatile("s_waitcnt vmcnt(" #n ")" ::: "memory")
#define WAITVM(n) WAITVM_(n)
#define LGKM0 asm volatile("s_waitcnt lgkmcnt(0)" ::: "memory")

#define STAGE_A(t_, buf_) do { \
    const float* s_ = gAsrc + (t_) * 32; \
    char* d_ = SHc + (buf_) * 4096; \
    async_copy16(s_,            d_); \
    async_copy16(s_ +  8 * ENC, d_ + 1024); \
    async_copy16(s_ + 16 * ENC, d_ + 2048); \
    async_copy16(s_ + 24 * ENC, d_ + 3072); } while (0)

#define STAGE_B(t_, buf_) do { \
    const unsigned short* s_ = Bsrc + (size_t)(t_) * 4096; \
    char* d_ = SHc + 12288 + (buf_) * 8192; \
    _Pragma("unroll") \
    for (int n_ = 0; n_ < 8; ++n_) \
      async_copy16(s_ + n_ * 512, d_ + n_ * 1024); } while (0)

#define STAGE_B16() do { \
    const unsigned short* s_ = Bsrc + (size_t)16 * 4096; \
    char* d_ = SHc + 28672; \
    _Pragma("unroll") \
    for (int n_ = 0; n_ < 8; ++n_) \
      async_copy16(s_ + n_ * 512, d_ + n_ * 1024); } while (0)

#define KSTEP(ab_, bb_, STAGECODE) do { \
    const char* Ab_ = SHc + (ab_) * 4096; \
    const char* Bb_ = SHc + 12288 + (bb_) * 8192; \
    f32x4 x00 = *(const f32x4*)(Ab_ + rsel * 128 + ca0 * 16); \
    f32x4 x01 = *(const f32x4*)(Ab_ + rsel * 128 + ca1 * 16); \
    f32x4 x10 = *(const f32x4*)(Ab_ + (16 + rsel) * 128 + ca0 * 16); \
    f32x4 x11 = *(const f32x4*)(Ab_ + (16 + rsel) * 128 + ca1 * 16); \
    bf16x8 bfr[8]; \
    _Pragma("unroll") \
    for (int n_ = 0; n_ < 8; ++n_) \
      bfr[n_] = *(const bf16x8*)(Bb_ + n_ * 1024 + lane * 16); \
    LGKM0; \
    STAGECODE; \
    bf16x8 af0, af1; \
    _Pragma("unroll") \
    for (int j_ = 0; j_ < 4; ++j_) { \
      af0[j_] = f2bf_fast(x00[j_]); af0[4 + j_] = f2bf_fast(x01[j_]); \
      af1[j_] = f2bf_fast(x10[j_]); af1[4 + j_] = f2bf_fast(x11[j_]); \
    } \
    _Pragma("unroll") \
    for (int n_ = 0; n_ < 8; ++n_) { \
      acc[0][n_] = __builtin_amdgcn_mfma_f32_16x16x32_bf16(af0, bfr[n_], acc[0][n_], 0, 0, 0); \
      acc[1][n_] = __builtin_amdgcn_mfma_f32_16x16x32_bf16(af1, bfr[n_], acc[1][n_], 0, 0, 0); \
    } } while (0)

  // ---- conv-tap A (step 16) via reg loads, issued before the counted stream ----
  f32x4 CV0, CV1, CV2, CV3;
  #pragma unroll
  for (int j = 0; j < 4; ++j) {
    int kk0 = grp * 8 + j, kk1 = grp * 8 + 4 + j;
    int p00 = row0 + rsel + kk0 - 15, p01 = row0 + rsel + kk1 - 15;
    CV0[j] = (kk0 < 31 && p00 >= 0 && p00 < T_LEN) ? prev[b * T_LEN + p00] : 0.f;
    CV1[j] = (kk1 < 31 && p01 >= 0 && p01 < T_LEN) ? prev[b * T_LEN + p01] : 0.f;
    CV2[j] = (kk0 < 31 && p00 + 16 >= 0 && p00 + 16 < T_LEN) ? prev[b * T_LEN + p00 + 16] : 0.f;
    CV3[j] = (kk1 < 31 && p01 + 16 >= 0 && p01 + 16 < T_LEN) ? prev[b * T_LEN + p01 + 16] : 0.f;
  }

  // ---- prologue stages (FIFO: B0 A0 B1 A1 A2 -> 28 outstanding + CV) ----
  STAGE_B(0, 0); STAGE_A(0, 0);
  STAGE_B(1, 1); STAGE_A(1, 1);
  STAGE_A(2, 2);

  // ---- 17 steps; A buf = t%3, B buf = t%2; stage(t+2 B, t+3 A) into just-read bufs ----
  WAITVM(16); KSTEP(0, 0, { STAGE_B(2, 0);  STAGE_A(3, 0);  });  // t=0
  WAITVM(16); KSTEP(1, 1, { STAGE_B(3, 1);  STAGE_A(4, 1);  });  // t=1
  WAITVM(16); KSTEP(2, 0, { STAGE_B(4, 0);  STAGE_A(5, 2);  });  // t=2
  WAITVM(16); KSTEP(0, 1, { STAGE_B(5, 1);  STAGE_A(6, 0);  });  // t=3
  WAITVM(16); KSTEP(1, 0, { STAGE_B(6, 0);  STAGE_A(7, 1);  });  // t=4
  WAITVM(16); KSTEP(2, 1, { STAGE_B(7, 1);  STAGE_A(8, 2);  });  // t=5
  WAITVM(16); KSTEP(0, 0, { STAGE_B(8, 0);  STAGE_A(9, 0);  });  // t=6
  WAITVM(16); KSTEP(1, 1, { STAGE_B(9, 1);  STAGE_A(10, 1); });  // t=7
  WAITVM(16); KSTEP(2, 0, { STAGE_B(10, 0); STAGE_A(11, 2); });  // t=8
  WAITVM(16); KSTEP(0, 1, { STAGE_B(11, 1); STAGE_A(12, 0); });  // t=9
  WAITVM(16); KSTEP(1, 0, { STAGE_B(12, 0); STAGE_A(13, 1); });  // t=10
  WAITVM(16); KSTEP(2, 1, { STAGE_B(13, 1); STAGE_A(14, 2); });  // t=11
  WAITVM(16); KSTEP(0, 0, { STAGE_B(14, 0); STAGE_A(15, 0); });  // t=12
  WAITVM(16); KSTEP(1, 1, { STAGE_B(15, 1); STAGE_B16();    });  // t=13
  WAITVM(20); KSTEP(2, 0, { });                                  // t=14  (drops A14,B14)
  WAITVM(8);  KSTEP(0, 1, { });                                  // t=15  (drops A15,B15)
  {  // t=16: conv-tap step; B16 from its LDS slot
    WAITVM(0);
    const char* Bb = SHc + 28672;
    bf16x8 bfr[8];
    #pragma unroll
    for (int n = 0; n < 8; ++n)
      bfr[n] = *(const bf16x8*)(Bb + n * 1024 + lane * 16);
    LGKM0;
    bf16x8 af0, af1;
    #pragma unroll
    for (int j = 0; j < 4; ++j) {
      af0[j] = f2bf_fast(CV0[j]); af0[4 + j] = f2bf_fast(CV1[j]);
      af1[j] = f2bf_fast(CV2[j]); af1[4 + j] = f2bf_fast(CV3[j]);
    }
    #pragma unroll
    for (int n = 0; n < 8; ++n) {
      acc[0][n] = __builtin_amdgcn_mfma_f32_16x16x32_bf16(af0, bfr[n], acc[0][n], 0, 0, 0);
      acc[1][n] = __builtin_amdgcn_mfma_f32_16x16x32_bf16(af1, bfr[n], acc[1][n], 0, 0, 0);
    }
  }

  // ---- epilogue: scores = sum_c V[c]*tanh(acc + pq[c]) ----
  float* e_vals = (float*)(SHc + 36864);
  float psum[2][4];
  #pragma unroll
  for (int m = 0; m < 2; ++m)
    #pragma unroll
    for (int i = 0; i < 4; ++i) psum[m][i] = 0.f;
  #pragma unroll
  for (int n = 0; n < 8; ++n) {
    int c = n * 16 + rsel;
    float pqv = pq[b * ATT + c];
    float vv = Vv[c];
    #pragma unroll
    for (int m = 0; m < 2; ++m)
      #pragma unroll
      for (int i = 0; i < 4; ++i)
        psum[m][i] += vv * fast_tanh(acc[m][n][i] + pqv);
  }
  #pragma unroll
  for (int m = 0; m < 2; ++m)
    #pragma unroll
    for (int i = 0; i < 4; ++i) {
      float v = psum[m][i];
      v += __shfl_xor(v, 1, 64);
      v += __shfl_xor(v, 2, 64);
      v += __shfl_xor(v, 4, 64);
      v += __shfl_xor(v, 8, 64);
      psum[m][i] = v;
    }
  float esum = 0.f;
  if (rsel == 0) {
    #pragma unroll
    for (int m = 0; m < 2; ++m)
      #pragma unroll
      for (int i = 0; i < 4; ++i) {
        int r = m * 16 + grp * 4 + i;
        int gr = b * T_LEN + row0 + r;
        float e = (mask[gr] == 0) ? 0.f : __expf(psum[m][i]);
        wout[gr] = e;
        e_vals[r] = e;
        esum += e;
      }
  }
  esum += __shfl_xor(esum, 16, 64);
  esum += __shfl_xor(esum, 32, 64);
  if (lane == 0) dpart[bid] = esum;
  __syncthreads();

  // ---- partial context over own 32 rows: branch-free, unrolled (tile L2-hot) ----
  {
    const float* kb = keys + ((size_t)b * T_LEN + row0) * ENC + lane * 8;
    f32x4 c0 = (f32x4)0.f, c1 = (f32x4)0.f;
    #pragma unroll
    for (int r = 0; r < 32; ++r) {
      float e = e_vals[r];
      f32x4 k0 = *(const f32x4*)(kb + (size_t)r * ENC);
      f32x4 k1 = *(const f32x4*)(kb + (size_t)r * ENC + 4);
      c0 += e * k0;
      c1 += e * k1;
    }
    *(f32x4*)(cpart + (size_t)bid * ENC + lane * 8) = c0;
    *(f32x4*)(cpart + (size_t)bid * ENC + lane * 8 + 4) = c1;
  }
}

// ---------------- finalize: normalize weights + reduce context partials
__global__ __launch_bounds__(256) void lsa_finalize(
    const float* __restrict__ dpart, const float* __restrict__ cpart,
    float* __restrict__ out) {
  int b = blockIdx.x, tid = threadIdx.x;
  float d = 0.f;
  #pragma unroll
  for (int i = 0; i < NTB; ++i) d += dpart[b * NTB + i];
  float inv = 1.f / d;
  for (int e = tid; e < ENC; e += 256) {
    float c = 0.f;
    #pragma unroll
    for (int i = 0; i < NTB; ++i) c += cpart[((size_t)(b * NTB + i)) * ENC + e];
    out[b * ENC + e] = c * inv;
  }
  float* wrow = out + NB * ENC + (size_t)b * T_LEN;
  for (int t = tid; t < T_LEN; t += 256) wrow[t] *= inv;
}

extern "C" void kernel_launch(void* const* d_in, const int* in_sizes, int n_in,
                              void* d_out, int out_size, void* d_ws, size_t ws_size,
                              hipStream_t stream) {
  const float* query  = (const float*)d_in[0];
  const float* keys   = (const float*)d_in[1];
  const float* prev   = (const float*)d_in[2];
  const int*   mask   = (const int*)d_in[3];
  const float* W1     = (const float*)d_in[4];
  const float* W2     = (const float*)d_in[5];
  const float* V      = (const float*)d_in[6];
  const float* convw  = (const float*)d_in[7];
  const float* ldense = (const float*)d_in[8];
  float* out = (float*)d_out;

  char* ws = (char*)d_ws;
  unsigned short* Bl = (unsigned short*)ws;                       // 139264 B
  float* pq    = (float*)(ws + 139264);                           // 32768 B
  float* dpart = (float*)(ws + 139264 + 32768);                   // 16384 B
  float* cpart = (float*)(ws + 139264 + 32768 + 16384);           // 8 MB

  prep<<<dim3(192), dim3(128), 0, stream>>>(query, W2, W1, convw, ldense, pq, Bl);
  lsa_main<<<dim3(NB * NTB), dim3(64), 0, stream>>>(keys, prev, mask, Bl, pq, V,
                                                    out + NB * ENC, dpart, cpart);
  lsa_finalize<<<dim3(NB), dim3(256), 0, stream>>>(dpart, cpart, out);
}

// Round 14
// 129.762 us; speedup vs baseline: 1.1144x; 1.0519x over previous
//
#include <hip/hip_runtime.h>

typedef __attribute__((ext_vector_type(4))) float f32x4;
typedef __attribute__((ext_vector_type(2))) float f32x2;
typedef __attribute__((ext_vector_type(8))) short bf16x8;

#define T_LEN 2048
#define ENC   512
#define DEC   1024
#define ATT   128
#define NB    64
#define BM    128
#define BK    32
#define NXB   (T_LEN / BM)   // 16

typedef unsigned int u32;
typedef __attribute__((address_space(1))) const u32 gu32;
typedef __attribute__((address_space(3))) u32 lu32;

__device__ __forceinline__ void async_copy16(const void* g, void* l) {
  __builtin_amdgcn_global_load_lds((gu32*)g, (lu32*)l, 16, 0, 0);
}

__device__ __forceinline__ unsigned short f2bf_rne(float x) {
  unsigned int u = __builtin_bit_cast(unsigned int, x);
  u += 0x7fff + ((u >> 16) & 1);
  return (unsigned short)(u >> 16);
}
// round-half-up: same 0.5-ulp max error, 2 VALU ops
__device__ __forceinline__ short f2bf_fast(float x) {
  unsigned int u = __builtin_bit_cast(unsigned int, x);
  return (short)((u + 0x8000u) >> 16);
}

__device__ __forceinline__ float fast_tanh(float x) {
  float e = __expf(2.f * x);
  return 1.f - 2.f / (e + 1.f);    // robust at +-inf
}

// ---------------- prep: pq = query@W2 (blocks 0..63); Bl chunk-major (blocks 64..191)
// Bl layout: step t (0..16), chunk c=kk>>3 (0..3), col a (0..127), 8 shorts (kk&7)
// flat short index: ((t*4 + c)*128 + a)*8 + (kk&7)   -> staging is identity-mapped
__global__ __launch_bounds__(128) void prep(
    const float* __restrict__ query, const float* __restrict__ W2,
    const float* __restrict__ W1, const float* __restrict__ convw,
    const float* __restrict__ ldense,
    float* __restrict__ pq, unsigned short* __restrict__ Bl) {
  int bidx = blockIdx.x;
  if (bidx < NB) {
    int a = threadIdx.x;
    const float* q = query + bidx * DEC;
    float a0 = 0.f, a1 = 0.f, a2 = 0.f, a3 = 0.f;
    for (int d = 0; d < DEC; d += 4) {
      a0 += q[d]     * W2[(d)     * ATT + a];
      a1 += q[d + 1] * W2[(d + 1) * ATT + a];
      a2 += q[d + 2] * W2[(d + 2) * ATT + a];
      a3 += q[d + 3] * W2[(d + 3) * ATT + a];
    }
    pq[bidx * ATT + a] = (a0 + a1) + (a2 + a3);
  } else {
    int a = bidx - NB;   // output column 0..127
    for (int k = threadIdx.x; k < 17 * BK; k += 128) {
      float v = 0.f;
      if (k < 512) {
        v = W1[k * ATT + a];
      } else if (k < 543) {
        int kc = k - 512;
        #pragma unroll
        for (int f = 0; f < 32; ++f) v += convw[f * 31 + kc] * ldense[f * ATT + a];
      }
      int kt = k >> 5, kk = k & 31;
      Bl[(((kt * 4) + (kk >> 3)) * 128 + a) * 8 + (kk & 7)] = f2bf_rne(v);
    }
  }
}

// ---------------- main: depth-2 counted-vmcnt pipeline, A+B staged via global_load_lds
__global__ __launch_bounds__(256, 2) void lsa_main(
    const float* __restrict__ keys, const float* __restrict__ prev,
    const int* __restrict__ mask, const unsigned short* __restrict__ Bl,
    const float* __restrict__ pq, const float* __restrict__ Vv,
    float* __restrict__ wout, float* __restrict__ dpart, float* __restrict__ cpart) {
  __shared__ float Abuf[3][BM * BK];            // 3 x 16 KB fp32, chunk-swizzled
  __shared__ unsigned short Bbuf[3][ATT * BK];  // 3 x 8 KB bf16, chunk-major
  __shared__ float s_red[2][BM];
  __shared__ float e_vals[BM];

  const int tid = threadIdx.x;
  const int b = blockIdx.y;
  const int trow0 = blockIdx.x * BM;
  const int bid = b * NXB + blockIdx.x;

  const int lane = tid & 63;
  const int w = tid >> 6;
  const int wr = w >> 1, wc = w & 1;          // 2x2 waves, wave tile 64x64
  const int rsel = lane & 15, grp = lane >> 4;

  // A staging: lane covers row (w*32 + i*8 + lr), phys 16B chunk cp holds logical cp^lr
  const int lr = lane >> 3, cp = lane & 7;
  const int gc = cp ^ lr;
  const float* gA = keys + ((size_t)b * T_LEN + trow0 + w * 32 + lr) * ENC + gc * 4;

  // A fragment read: row r = wr*64 + m*16 + rsel; logical chunks 2g,2g+1; (r&7)==(rsel&7)
  const int rx = rsel & 7;
  const int ca0 = (2 * grp) ^ rx, ca1 = (2 * grp + 1) ^ rx;
  const int arow_base = (wr * 64 + rsel) * BK;

  // B fragment read (chunk-major): shorts offset (grp*128 + col)*8
  const int bcol_base = wc * 64 + rsel;

  f32x4 acc[4][4];
  #pragma unroll
  for (int m = 0; m < 4; ++m)
    #pragma unroll
    for (int n = 0; n < 4; ++n) acc[m][n] = (f32x4)0.f;

  // stage tile t into buffer buf: 4 A-loads + 2 B-loads per thread (6 vmem insts/wave)
  // NOTE: global source must be PER-LANE (gA embeds lane; B adds lane*8 shorts = lane*16B);
  // LDS dest is wave-uniform base (+ lane*16B applied by HW).
  auto STAGE = [&](int t, int buf) {
    const float* gt = gA + t * BK;
    float* dstA = &Abuf[buf][0];
    #pragma unroll
    for (int i = 0; i < 4; ++i)
      async_copy16(gt + (size_t)i * 8 * ENC, &dstA[(w * 4 + i) * 256]);
    const unsigned short* gBt = Bl + (size_t)t * (ATT * BK) + w * 1024 + lane * 8;
    unsigned short* dstB = &Bbuf[buf][0];
    #pragma unroll
    for (int j = 0; j < 2; ++j)
      async_copy16(gBt + j * 512, &dstB[w * 1024 + j * 512]);
  };

  auto COMPUTE = [&](int buf) {
    const unsigned short* Bb = &Bbuf[buf][0];
    bf16x8 bfr[4];
    #pragma unroll
    for (int n = 0; n < 4; ++n)
      bfr[n] = *reinterpret_cast<const bf16x8*>(&Bb[(grp * 128 + bcol_base + n * 16) * 8]);
    const float* Ab = &Abuf[buf][0];
    #pragma unroll
    for (int m = 0; m < 4; ++m) {
      f32x4 x0 = *reinterpret_cast<const f32x4*>(&Ab[arow_base + m * 16 * BK + ca0 * 4]);
      f32x4 x1 = *reinterpret_cast<const f32x4*>(&Ab[arow_base + m * 16 * BK + ca1 * 4]);
      bf16x8 af;
      #pragma unroll
      for (int j = 0; j < 4; ++j) { af[j] = f2bf_fast(x0[j]); af[4 + j] = f2bf_fast(x1[j]); }
      #pragma unroll
      for (int n = 0; n < 4; ++n)
        acc[m][n] = __builtin_amdgcn_mfma_f32_16x16x32_bf16(af, bfr[n], acc[m][n], 0, 0, 0);
    }
  };

  // ---- prologue: stage tiles 0,1; wait tile0 (leave tile1 in flight) ----
  STAGE(0, 0);
  STAGE(1, 1);
  asm volatile("s_waitcnt vmcnt(6)" ::: "memory");
  __builtin_amdgcn_s_barrier();
  __builtin_amdgcn_sched_barrier(0);

  // ---- main loop t = 0..13: issue stage(t+2), compute(t), wait stage(t+1) ----
  #pragma unroll
  for (int t = 0; t < 14; ++t) {
    STAGE(t + 2, (t + 2) % 3);
    COMPUTE(t % 3);
    asm volatile("s_waitcnt vmcnt(6)" ::: "memory");
    __builtin_amdgcn_s_barrier();
    __builtin_amdgcn_sched_barrier(0);
  }

  // ---- t = 14: stage conv tile (t=16 -> buf 1): B via gload_lds, A via ds_write ----
  {
    const unsigned short* gBt = Bl + (size_t)16 * (ATT * BK) + w * 1024 + lane * 8;
    unsigned short* dstB = &Bbuf[1][0];
    #pragma unroll
    for (int j = 0; j < 2; ++j)
      async_copy16(gBt + j * 512, &dstB[w * 1024 + j * 512]);
    // conv A: A16[r][kk] = prev[trow0 + r + kk - 15], kk<31, swizzled like regular A
    const int r_ = tid >> 1, kh_ = tid & 1;
    const int rx2_ = r_ & 7;
    float* dstA = &Abuf[1][r_ * BK];
    #pragma unroll
    for (int jc = 0; jc < 4; ++jc) {
      int c = kh_ * 4 + jc;
      f32x4 v;
      #pragma unroll
      for (int q = 0; q < 4; ++q) {
        int kk = c * 4 + q;
        int pos = trow0 + r_ + kk - 15;
        v[q] = (kk < 31 && pos >= 0 && pos < T_LEN) ? prev[b * T_LEN + pos] : 0.f;
      }
      *reinterpret_cast<f32x4*>(&dstA[(c ^ rx2_) * 4]) = v;
    }
    COMPUTE(14 % 3);
    __syncthreads();   // full vmcnt+lgkm drain: tiles 15,16 all resident after this
  }

  // ---- t = 15, 16: everything resident, no more barriers needed ----
  COMPUTE(15 % 3);
  COMPUTE(16 % 3);

  // ---- epilogue: scores = sum_a V[a]*tanh(acc + pq) ----
  float psum[4][4];
  #pragma unroll
  for (int m = 0; m < 4; ++m)
    #pragma unroll
    for (int i = 0; i < 4; ++i) psum[m][i] = 0.f;
  #pragma unroll
  for (int n = 0; n < 4; ++n) {
    int c = wc * 64 + n * 16 + rsel;
    float pqv = pq[b * ATT + c];
    float vv = Vv[c];
    #pragma unroll
    for (int m = 0; m < 4; ++m)
      #pragma unroll
      for (int i = 0; i < 4; ++i)
        psum[m][i] += vv * fast_tanh(acc[m][n][i] + pqv);
  }
  #pragma unroll
  for (int m = 0; m < 4; ++m)
    #pragma unroll
    for (int i = 0; i < 4; ++i) {
      float v = psum[m][i];
      v += __shfl_xor(v, 1, 64);
      v += __shfl_xor(v, 2, 64);
      v += __shfl_xor(v, 4, 64);
      v += __shfl_xor(v, 8, 64);
      psum[m][i] = v;
    }
  if (rsel == 0) {
    #pragma unroll
    for (int m = 0; m < 4; ++m)
      #pragma unroll
      for (int i = 0; i < 4; ++i)
        s_red[wc][wr * 64 + m * 16 + grp * 4 + i] = psum[m][i];
  }
  __syncthreads();

  if (tid < BM) {
    int trow = trow0 + tid;
    float s = s_red[0][tid] + s_red[1][tid];
    float e = (mask[b * T_LEN + trow] == 0) ? 0.f : __expf(s);
    wout[b * T_LEN + trow] = e;       // unnormalized; finalize scales
    e_vals[tid] = e;
  }
  __syncthreads();

  if (tid < 64) {
    float v = e_vals[tid] + e_vals[tid + 64];
    #pragma unroll
    for (int off = 32; off; off >>= 1) v += __shfl_xor(v, off, 64);
    if (tid == 0) dpart[bid] = v;
  }

  // ---- partial context: branch-free, float2, L2/L3-hot re-read of own tile ----
  {
    const float* kcol = keys + ((size_t)b * T_LEN + trow0) * ENC + 2 * tid;
    f32x2 cacc; cacc.x = 0.f; cacc.y = 0.f;
    #pragma unroll 8
    for (int r = 0; r < BM; ++r) {
      float e = e_vals[r];
      f32x2 kv = *reinterpret_cast<const f32x2*>(kcol + (size_t)r * ENC);
      cacc.x += e * kv.x;
      cacc.y += e * kv.y;
    }
    *reinterpret_cast<f32x2*>(cpart + (size_t)bid * ENC + 2 * tid) = cacc;
  }
}

// ---------------- finalize: normalize weights + reduce context partials
__global__ __launch_bounds__(256) void lsa_finalize(
    const float* __restrict__ dpart, const float* __restrict__ cpart,
    float* __restrict__ out) {
  int b = blockIdx.x, tid = threadIdx.x;
  float d = 0.f;
  #pragma unroll
  for (int i = 0; i < NXB; ++i) d += dpart[b * NXB + i];
  float inv = 1.f / d;
  for (int e = tid; e < ENC; e += 256) {
    float c = 0.f;
    #pragma unroll
    for (int i = 0; i < NXB; ++i) c += cpart[((size_t)(b * NXB + i)) * ENC + e];
    out[b * ENC + e] = c * inv;
  }
  float* wrow = out + NB * ENC + (size_t)b * T_LEN;
  for (int t = tid; t < T_LEN; t += 256) wrow[t] *= inv;
}

extern "C" void kernel_launch(void* const* d_in, const int* in_sizes, int n_in,
                              void* d_out, int out_size, void* d_ws, size_t ws_size,
                              hipStream_t stream) {
  const float* query  = (const float*)d_in[0];
  const float* keys   = (const float*)d_in[1];
  const float* prev   = (const float*)d_in[2];
  const int*   mask   = (const int*)d_in[3];
  const float* W1     = (const float*)d_in[4];
  const float* W2     = (const float*)d_in[5];
  const float* V      = (const float*)d_in[6];
  const float* convw  = (const float*)d_in[7];
  const float* ldense = (const float*)d_in[8];
  float* out = (float*)d_out;

  char* ws = (char*)d_ws;
  unsigned short* Bl = (unsigned short*)ws;                       // 139264 B
  float* pq    = (float*)(ws + 139264);                           // 32768 B
  float* dpart = (float*)(ws + 139264 + 32768);                   // 4096 B
  float* cpart = (float*)(ws + 139264 + 32768 + 4096);            // 2 MB

  prep<<<dim3(192), dim3(128), 0, stream>>>(query, W2, W1, convw, ldense, pq, Bl);
  dim3 grid(NXB, NB);
  lsa_main<<<grid, dim3(256), 0, stream>>>(keys, prev, mask, Bl, pq, V,
                                           out + NB * ENC, dpart, cpart);
  lsa_finalize<<<dim3(NB), dim3(256), 0, stream>>>(dpart, cpart, out);
}